// Round 10
// baseline (1490.063 us; speedup 1.0000x reference)
//
#include <hip/hip_runtime.h>

typedef short s16x8 __attribute__((ext_vector_type(8)));
typedef float f32x4 __attribute__((ext_vector_type(4)));
typedef float f32x16 __attribute__((ext_vector_type(16)));

// device-global scratch (outside d_ws; fully rewritten every launch)
__device__ short g_wbuf[18874368];  // bf16 weights, all layers: inproj|outw|ffw1|ffw2
__device__ short g_srcb[1048576];   // src as bf16 (16384 x 64)
__device__ short g_inpwb[32768];    // inp_w as bf16 (512 x 64)
__device__ float g_pe[262144];      // positional encoding (512 x 512)
__device__ float g_hpart[256];      // head partials

__device__ inline float b2f(short s) {
  union { unsigned int u; float f; } v;
  v.u = ((unsigned int)(unsigned short)s) << 16;
  return v.f;
}
__device__ inline short f2b(float f) {
  union { float f; unsigned int u; } v; v.f = f;
  unsigned int r = (v.u + 0x7fffu + ((v.u >> 16) & 1u)) >> 16;
  return (short)r;
}
__device__ inline s16x8 pack8(float4 a, float4 b) {
  s16x8 r;
  r[0] = f2b(a.x); r[1] = f2b(a.y); r[2] = f2b(a.z); r[3] = f2b(a.w);
  r[4] = f2b(b.x); r[5] = f2b(b.y); r[6] = f2b(b.z); r[7] = f2b(b.w);
  return r;
}

__device__ inline f32x4 mfma16(s16x8 a, s16x8 b, f32x4 c) {
  return __builtin_amdgcn_mfma_f32_16x16x32_bf16(a, b, c, 0, 0, 0);
}
__device__ inline f32x16 mfma32(s16x8 a, s16x8 b, f32x16 c) {
  return __builtin_amdgcn_mfma_f32_32x32x16_bf16(a, b, c, 0, 0, 0);
}

typedef const __attribute__((address_space(1))) void* as1cptr;
typedef __attribute__((address_space(3))) void* as3ptr;
__device__ inline void gl2lds16(const short* g, short* l) {
  __builtin_amdgcn_global_load_lds((as1cptr)g, (as3ptr)l, 16, 0, 0);
}

// ---------------- fp32 -> bf16 conversion kernels --------------------------
__global__ void __launch_bounds__(256)
cvt2_kernel(const float* __restrict__ i0, const float* __restrict__ i1) {
  const int b = blockIdx.x;
  const float* src; short* dst; int base;
  if (b < 512) { src = i0; dst = g_srcb; base = b; }
  else         { src = i1; dst = g_inpwb; base = b - 512; }
  const int idx = (base * 256 + threadIdx.x) * 8;
  float4 a = *(const float4*)(src + idx);
  float4 c = *(const float4*)(src + idx + 4);
  *(s16x8*)(dst + idx) = pack8(a, c);
}

// all 6 layers' weights: inproj(2304) | outw(768) | ffw1(3072) | ffw2(3072)
__global__ void __launch_bounds__(256)
cvt6_kernel(const float* __restrict__ i0, const float* __restrict__ i1,
            const float* __restrict__ i2, const float* __restrict__ i3) {
  const int b = blockIdx.x;
  const float* src; short* dst; int base;
  if (b < 2304)      { src = i0; dst = g_wbuf;            base = b; }
  else if (b < 3072) { src = i1; dst = g_wbuf +  4718592; base = b - 2304; }
  else if (b < 6144) { src = i2; dst = g_wbuf +  6291456; base = b - 3072; }
  else               { src = i3; dst = g_wbuf + 12582912; base = b - 6144; }
  const int idx = (base * 256 + threadIdx.x) * 8;
  float4 a = *(const float4*)(src + idx);
  float4 c = *(const float4*)(src + idx + 4);
  *(s16x8*)(dst + idx) = pack8(a, c);
}

// ---------------- PE table: g_pe[s][n] ------------------------------------
__global__ void __launch_bounds__(256)
pe_kernel() {
  const int s = blockIdx.x;
  const int n0 = threadIdx.x * 2;
  const float ang = (float)s * expf((float)n0 * -0.0179889460390160f);
  g_pe[s * 512 + n0]     = sinf(ang);
  g_pe[s * 512 + n0 + 1] = cosf(ang);
}

// ---------------- GEMM: C[M,N] = A[M,K] @ W[N,K]^T + epilogue -------------
// BK=64, XOR-swizzled gl2lds staging. Grid remap (R6, confirmed ~-100us):
// supertiles of 32 bm-panels x all bn keep the in-flight working set at
// ~4MB A slice + <=2MB weights (L2/L3-hot). EPI: 0=+bias; 1=relu; 2=embed.
template <int EPI>
__global__ void __launch_bounds__(256, 3)
gemm_bt(const short* __restrict__ Ain, int woff, const float* __restrict__ bias,
        short* __restrict__ C, int M, int N, int K) {
  __shared__ short As[128 * 64];   // 16 KB
  __shared__ short Bs[128 * 64];   // 16 KB
  const int tid  = threadIdx.x;
  const int lane = tid & 63;
  const int wave = tid >> 6;
  const int wr = (wave >> 1) << 6;
  const int wc = (wave & 1) << 6;
  const int l31 = lane & 31;
  const int half = lane >> 5;          // 0/1: k-half within K=16 step
  const int bnc = N >> 7;              // bn panel count
  const int per = bnc << 5;            // 32 * bnc blocks per supertile
  const int g   = blockIdx.x / per;    // supertile 0..3
  const int rix = blockIdx.x - g * per;
  const int bm  = (g << 5) + (rix & 31);
  const int bn  = rix >> 5;

  const short* A = (EPI == 2) ? (const short*)g_srcb : Ain;
  const short* W = (EPI == 2) ? (const short*)g_inpwb : (const short*)(g_wbuf + woff);

  int srow[4], soff[4];
#pragma unroll
  for (int i = 0; i < 4; ++i) {
    const int u = i * 256 + tid;
    srow[i] = u >> 3;
    soff[i] = ((u & 7) ^ ((u >> 3) & 7)) << 3;
  }
  const int rsw = lane & 7;            // read-side swizzle key (row&7)
  f32x16 acc[2][2] = {};

  for (int k0 = 0; k0 < K; k0 += 64) {
#pragma unroll
    for (int i = 0; i < 4; ++i) {
      gl2lds16(A + (size_t)(bm * 128 + srow[i]) * K + k0 + soff[i],
               As + (i * 256 + tid) * 8);
      gl2lds16(W + (size_t)(bn * 128 + srow[i]) * K + k0 + soff[i],
               Bs + (i * 256 + tid) * 8);
    }
    __syncthreads();
#pragma unroll
    for (int ks = 0; ks < 4; ++ks) {
      const int rchunk = ((ks * 2 + half) ^ rsw) * 8;
      s16x8 af[2], bfr[2];
#pragma unroll
      for (int i = 0; i < 2; ++i)
        af[i] = *(const s16x8*)(As + (wr + i * 32 + l31) * 64 + rchunk);
#pragma unroll
      for (int j = 0; j < 2; ++j)
        bfr[j] = *(const s16x8*)(Bs + (wc + j * 32 + l31) * 64 + rchunk);
#pragma unroll
      for (int i = 0; i < 2; ++i)
#pragma unroll
        for (int j = 0; j < 2; ++j)
          acc[i][j] = mfma32(af[i], bfr[j], acc[i][j]);
    }
    __syncthreads();
  }

#pragma unroll
  for (int j = 0; j < 2; ++j) {
    const int col = bn * 128 + wc + j * 32 + l31;
    const float bv = bias[col];
#pragma unroll
    for (int i = 0; i < 2; ++i) {
      const int rbase = bm * 128 + wr + i * 32 + half * 4;
#pragma unroll
      for (int r = 0; r < 16; ++r) {
        const int row = rbase + (r & 3) + 8 * (r >> 2);
        float v = acc[i][j][r] + bv;
        if (EPI == 1) v = fmaxf(v, 0.0f);
        if (EPI == 2) {
          const int s = row & 511;
          v = (acc[i][j][r] + bv) * 22.62741699796952f + g_pe[s * 512 + col];
        }
        C[(size_t)row * N + col] = f2b(v);
      }
    }
  }
}

// ---------------- attention: v12 — v7 schedule + arithmetic-only trims ----
// Schedule identical to verified v7 (63.5us): 3 barriers/round, online
// softmax, single-Kb staging after B1, truncation-pack P. Changes are
// pure per-element arithmetic (v8/v10 failed by changing the SCHEDULE):
//  (a) Q pre-scaled by 0.125 at load (exponent shift; products scale
//      exactly in the f32 MFMA accumulator -> bit-identical scores).
//      Removes the x0.125 from every exp arg and from the rescale path.
//  (b) psum computed by MFMA ones-column: psacc = mfma16(pf, 1.0bf16,
//      psacc) inside the PV loop (4 extra MFMA/round on the idle matrix
//      pipe). Sums EXACTLY the truncated bf16 P that PV consumes; kills
//      32 VALU ops/round/thread + the entire final psum shuffle/rcomb
//      combine + one barrier. psacc follows the same online x scl
//      recurrence psum did.
__global__ void __launch_bounds__(512, 4)
attn_kernel(const short* __restrict__ qkv, short* __restrict__ ctx) {
  __shared__ short Kb[8192];         // K [128 key][64 d], chunk-swizzled
  __shared__ short VT[8192];         // V^T [64 d][128 key], swizzled
  __shared__ short Pt[8192];         // P [64 q][128 key], swizzled
  __shared__ float rcomb[2][4][16];  // [nh][mt][row16]: per-round max
  const int tid = threadIdx.x;
  const int lane = tid & 63, wave = tid >> 6;
  const int ml = lane & 15, quad = lane >> 4;
  const int mt = wave >> 1, nh = wave & 1;
  const int qt = (blockIdx.x >> 3) & 7;
  const int bh = (blockIdx.x & 7) | ((blockIdx.x >> 6) << 3);
  const int b = bh >> 3, h = bh & 7;
  const size_t basebs = (size_t)b * 512 * 1536;
  const int hoff = h * 64;

  // Q fragments, pre-scaled by 0.125 (exact: exponent-3; f2b exact here)
  s16x8 qf0, qf1;
  {
    const int qrow = qt * 64 + mt * 16 + ml;
    const short* qp = qkv + basebs + (size_t)qrow * 1536 + hoff;
    qf0 = *(const s16x8*)(qp + quad * 8);
    qf1 = *(const s16x8*)(qp + 32 + quad * 8);
#pragma unroll
    for (int e = 0; e < 8; ++e) {
      qf0[e] = f2b(b2f(qf0[e]) * 0.125f);
      qf1[e] = f2b(b2f(qf1[e]) * 0.125f);
    }
  }

  // ones fragment (bf16 1.0) for the psum MFMA column
  s16x8 onesf;
#pragma unroll
  for (int e = 0; e < 8; ++e) onesf[e] = (short)0x3F80;

  // K staging geometry: tile [128 key][64 d], 2 gl2lds16 per thread.
  // LDS slot u holds global d-chunk (u&7)^(row&7) of key-row u>>3.
  const int srow0 = tid >> 3, srow1 = srow0 + 64;
  const int soff0 = (((tid & 7) ^ (srow0 & 7)) << 3);
  const int soff1 = (((tid & 7) ^ (srow1 & 7)) << 3);
  const short* kbase = qkv + basebs + 512 + hoff;

  // V geometry: thread covers keys {2*vkp, 2*vkp+1} x d [vd8, vd8+8)
  const int vkp = tid & 63, vd8 = (tid >> 6) << 3;
  const short* vbase = qkv + basebs + 1024 + hoff + vd8;

  // prologue: stage K(0)
  gl2lds16(kbase + (size_t)srow0 * 1536 + soff0, &Kb[tid * 8]);
  gl2lds16(kbase + (size_t)srow1 * 1536 + soff1, &Kb[(512 + tid) * 8]);
  __syncthreads();

  f32x4 oacc[2] = {};
  f32x4 psacc = {};                  // softmax denominator via ones-column MFMA
  float mrun[4] = {-1e30f, -1e30f, -1e30f, -1e30f};

#pragma unroll 1
  for (int rr = 0; rr < 4; ++rr) {
    // issue V(rr) loads; QK^T below hides the latency; consumed this round
    const short* vp = vbase + (size_t)(rr * 128 + vkp * 2) * 1536;
    s16x8 va = *(const s16x8*)vp;
    s16x8 vb = *(const s16x8*)(vp + 1536);

    // QK^T (pre-scaled): 4 nt tiles x (2 mfma)
    f32x4 sc[4];
#pragma unroll
    for (int nt = 0; nt < 4; ++nt) {
      const int krow = nh * 64 + nt * 16 + ml;
      const short* kr = Kb + krow * 64;
      s16x8 kf0 = *(const s16x8*)(kr + ((quad ^ (ml & 7)) << 3));
      s16x8 kf1 = *(const s16x8*)(kr + (((quad + 4) ^ (ml & 7)) << 3));
      f32x4 s0 = {};
      s0 = mfma16(qf0, kf0, s0);
      s0 = mfma16(qf1, kf1, s0);
      sc[nt] = s0;
    }

    // build swizzled V^T(rr) in LDS (va/vb consumed here; no barrier crossed)
#pragma unroll
    for (int j = 0; j < 8; ++j) {
      const int d = vd8 + j;
      unsigned int u = (unsigned int)(unsigned short)va[j]
                     | ((unsigned int)(unsigned short)vb[j] << 16);
      *(unsigned int*)(VT + d * 128 + ((((vkp >> 2) ^ (d & 15)) << 3) | ((vkp & 3) << 1))) = u;
    }

    // wave-local tile row max over this round's 64 keys (per nh half)
    f32x4 tmx = sc[0];
#pragma unroll
    for (int nt = 1; nt < 4; ++nt)
#pragma unroll
      for (int r = 0; r < 4; ++r)
        tmx[r] = fmaxf(tmx[r], sc[nt][r]);
#pragma unroll
    for (int off = 1; off <= 8; off <<= 1)
#pragma unroll
      for (int r = 0; r < 4; ++r)
        tmx[r] = fmaxf(tmx[r], __shfl_xor(tmx[r], off));
    if (ml == 0) {
#pragma unroll
      for (int r = 0; r < 4; ++r)
        rcomb[nh][mt][quad * 4 + r] = tmx[r];
    }
    __syncthreads();                 // B1: rcomb + V^T(rr) visible; Kb reads done

    // stage K(rr+1) into the single Kb; lands during exp phase, drained at B2
    if (rr < 3) {
      const short* kb2 = kbase + (size_t)((rr + 1) * 128) * 1536;
      gl2lds16(kb2 + (size_t)srow0 * 1536 + soff0, &Kb[tid * 8]);
      gl2lds16(kb2 + (size_t)srow1 * 1536 + soff1, &Kb[(512 + tid) * 8]);
    }

    // online rescale (scores already scaled; no 0.125 factor)
#pragma unroll
    for (int r = 0; r < 4; ++r) {
      const float tm = fmaxf(rcomb[0][mt][quad * 4 + r],
                             rcomb[1][mt][quad * 4 + r]);
      const float mn = fmaxf(mrun[r], tm);
      const float scl = __expf(mrun[r] - mn);   // <=1; first round: exp(-huge)=0
      mrun[r] = mn;
      psacc[r] *= scl;
      oacc[0][r] *= scl;
      oacc[1][r] *= scl;
    }

    // exp -> swizzled Pt (truncation to bf16; denominator comes from the
    // ones-column MFMA below, summing the SAME truncated values PV uses)
#pragma unroll
    for (int nt = 0; nt < 4; ++nt) {
#pragma unroll
      for (int r = 0; r < 4; ++r) {
        union { float f; unsigned int u; } pu;
        pu.f = __expf(sc[nt][r] - mrun[r]);   // arg <= 0 exactly
        const short pb = (short)(pu.u >> 16);
        const int qrl = mt * 16 + quad * 4 + r;
        const int c = nh * 64 + nt * 16 + ml;
        Pt[qrl * 128 + ((((c >> 3) ^ (qrl & 15)) << 3) | (c & 7))] = pb;
      }
    }
    __syncthreads();                 // B2: Pt visible; K(rr+1) staged

    // PV + denominator: 4 k-chunks x (ones + 2 d-tiles)
    const int prow = mt * 16 + ml;
#pragma unroll
    for (int ks = 0; ks < 4; ++ks) {
      s16x8 pf = *(const s16x8*)(Pt + prow * 128 + ((((ks << 2) | quad) ^ ml) << 3));
      psacc = mfma16(pf, onesf, psacc);   // sum of P over this 32-key chunk
#pragma unroll
      for (int n2 = 0; n2 < 2; ++n2) {
        const int nd = (nh * 2 + n2) * 16 + ml;
        s16x8 vf = *(const s16x8*)(VT + nd * 128 + ((((ks << 2) | quad) ^ ml) << 3));
        oacc[n2] = mfma16(pf, vf, oacc[n2]);
      }
    }
    __syncthreads();                 // B3: PV reads done before next VT/Pt rewrite
  }

  // psacc[r] holds the FULL 512-key denominator for q-row quad*4+r:
  // each PV pass spans all 128 keys (both nh halves) and rounds cover 4x128.
  // Every lane's psacc is valid (all 16 output cols of the ones-MFMA equal).
#pragma unroll
  for (int r = 0; r < 4; ++r) {
    const float rl = 1.0f / psacc[r];
    const int grow = qt * 64 + mt * 16 + quad * 4 + r;
#pragma unroll
    for (int n2 = 0; n2 < 2; ++n2) {
      const int d = (nh * 2 + n2) * 16 + ml;
      ctx[((size_t)b * 512 + grow) * 512 + hoff + d] = f2b(oacc[n2][r] * rl);
    }
  }
}

// ---------------- residual + layernorm (in-place on x, fp32 params) -------
__global__ void __launch_bounds__(256)
ln_kernel(short* __restrict__ x, const short* __restrict__ o,
          const float* __restrict__ g, const float* __restrict__ bta) {
  const int row = blockIdx.x * 4 + (threadIdx.x >> 6);
  const int lane = threadIdx.x & 63;
  short* xp = x + (size_t)row * 512 + lane * 8;
  const short* op = o + (size_t)row * 512 + lane * 8;
  s16x8 xv = *(const s16x8*)xp;
  s16x8 ov = *(const s16x8*)op;
  float v[8]; float s = 0.f, s2 = 0.f;
#pragma unroll
  for (int e = 0; e < 8; ++e) {
    float f = b2f(xv[e]) + b2f(ov[e]);
    v[e] = f; s += f; s2 += f * f;
  }
#pragma unroll
  for (int off = 32; off >= 1; off >>= 1) {
    s += __shfl_xor(s, off);
    s2 += __shfl_xor(s2, off);
  }
  const float mean = s * (1.f / 512.f);
  const float var = s2 * (1.f / 512.f) - mean * mean;
  const float rstd = rsqrtf(var + 1e-5f);
  float4 g0 = *(const float4*)(g + lane * 8);
  float4 g1 = *(const float4*)(g + lane * 8 + 4);
  float4 b0 = *(const float4*)(bta + lane * 8);
  float4 b1 = *(const float4*)(bta + lane * 8 + 4);
  float gv[8] = {g0.x, g0.y, g0.z, g0.w, g1.x, g1.y, g1.z, g1.w};
  float bv[8] = {b0.x, b0.y, b0.z, b0.w, b1.x, b1.y, b1.z, b1.w};
  s16x8 outv;
#pragma unroll
  for (int e = 0; e < 8; ++e)
    outv[e] = f2b((v[e] - mean) * rstd * gv[e] + bv[e]);
  *(s16x8*)xp = outv;
}

// ---------------- head ----------------------------------------------------
__global__ void __launch_bounds__(256)
head1_kernel(const short* __restrict__ x, const float* __restrict__ w1,
             const float* __restrict__ b1, const float* __restrict__ w2) {
  const int bidx = blockIdx.x;
  const int b = bidx >> 3, seg = bidx & 7;
  const int tid = threadIdx.x;
  __shared__ float xl[512];
  __shared__ float red[256];
  for (int n = tid; n < 512; n += 256)
    xl[n] = b2f(x[((size_t)b * 512 + 511) * 512 + n]);
  __syncthreads();
  const int f = seg * 256 + tid;
  const float* wr = w1 + (size_t)f * 512;
  float hv = 0.f;
  for (int k8 = 0; k8 < 64; ++k8) {
    float4 wa = *(const float4*)(wr + k8 * 8);
    float4 wb = *(const float4*)(wr + k8 * 8 + 4);
    hv += xl[k8 * 8 + 0] * wa.x + xl[k8 * 8 + 1] * wa.y +
          xl[k8 * 8 + 2] * wa.z + xl[k8 * 8 + 3] * wa.w +
          xl[k8 * 8 + 4] * wb.x + xl[k8 * 8 + 5] * wb.y +
          xl[k8 * 8 + 6] * wb.z + xl[k8 * 8 + 7] * wb.w;
  }
  hv += b1[f];
  hv = fmaxf(hv, 0.f);
  red[tid] = hv * w2[f];
  __syncthreads();
  for (int stride = 128; stride > 0; stride >>= 1) {
    if (tid < stride) red[tid] += red[tid + stride];
    __syncthreads();
  }
  if (tid == 0) g_hpart[bidx] = red[0];
}

__global__ void __launch_bounds__(64)
head2_kernel(const float* __restrict__ b2, float* __restrict__ out) {
  const int t = threadIdx.x;
  if (t < 32) {
    float s = 0.f;
#pragma unroll
    for (int c = 0; c < 8; ++c) s += g_hpart[t * 8 + c];
    out[t] = s + b2[0];
  }
}

extern "C" void kernel_launch(void* const* d_in, const int* in_sizes, int n_in,
                              void* d_out, int out_size, void* d_ws, size_t ws_size,
                              hipStream_t stream) {
  (void)in_sizes; (void)n_in; (void)out_size; (void)ws_size;
  const float* src       = (const float*)d_in[0];
  const float* inp_w     = (const float*)d_in[1];
  const float* inp_b     = (const float*)d_in[2];
  const float* in_proj_w = (const float*)d_in[3];
  const float* in_proj_b = (const float*)d_in[4];
  const float* out_w     = (const float*)d_in[5];
  const float* out_b     = (const float*)d_in[6];
  const float* ff_w1     = (const float*)d_in[7];
  const float* ff_b1     = (const float*)d_in[8];
  const float* ff_w2     = (const float*)d_in[9];
  const float* ff_b2     = (const float*)d_in[10];
  const float* ln1_g     = (const float*)d_in[11];
  const float* ln1_b     = (const float*)d_in[12];
  const float* ln2_g     = (const float*)d_in[13];
  const float* ln2_b     = (const float*)d_in[14];
  const float* op_w1     = (const float*)d_in[15];
  const float* op_b1     = (const float*)d_in[16];
  const float* op_w2     = (const float*)d_in[17];
  const float* op_b2     = (const float*)d_in[18];

  short* ws   = (short*)d_ws;
  short* x    = ws;                              //  8,388,608
  short* qkv  = ws + 8388608;                    // 25,165,824
  short* ctx  = qkv + 25165824;                  //  8,388,608
  short* obuf = ctx + 8388608;                   //  8,388,608
  short* h    = qkv;                             // ff hidden spans qkv+ctx

  cvt2_kernel<<<528, 256, 0, stream>>>(src, inp_w);
  cvt6_kernel<<<9216, 256, 0, stream>>>(in_proj_w, out_w, ff_w1, ff_w2);
  pe_kernel<<<512, 256, 0, stream>>>();
  gemm_bt<2><<<512, 256, 0, stream>>>(nullptr, 0, inp_b, x, 16384, 512, 64);

  for (int l = 0; l < 6; ++l) {
    const int w_qkv = l * 786432;
    const int w_out = 4718592 + l * 262144;
    const int w_ff1 = 6291456 + l * 1048576;
    const int w_ff2 = 12582912 + l * 1048576;
    gemm_bt<0><<<1536, 256, 0, stream>>>(
        x, w_qkv, in_proj_b + l * 1536, qkv, 16384, 1536, 512);
    attn_kernel<<<2048, 512, 0, stream>>>(qkv, ctx);
    gemm_bt<0><<<512, 256, 0, stream>>>(
        ctx, w_out, out_b + l * 512, obuf, 16384, 512, 512);
    ln_kernel<<<4096, 256, 0, stream>>>(x, obuf, ln1_g + l * 512, ln1_b + l * 512);
    gemm_bt<1><<<2048, 256, 0, stream>>>(
        x, w_ff1, ff_b1 + l * 2048, h, 16384, 2048, 512);
    gemm_bt<0><<<512, 256, 0, stream>>>(
        h, w_ff2, ff_b2 + l * 512, obuf, 16384, 512, 2048);
    ln_kernel<<<4096, 256, 0, stream>>>(x, obuf, ln2_g + l * 512, ln2_b + l * 512);
  }
  head1_kernel<<<256, 256, 0, stream>>>(x, op_w1, op_b1, op_w2);
  head2_kernel<<<1, 64, 0, stream>>>(op_b2, (float*)d_out);
}

// Round 12
// 1429.567 us; speedup vs baseline: 1.0423x; 1.0423x over previous
//
#include <hip/hip_runtime.h>

typedef short s16x8 __attribute__((ext_vector_type(8)));
typedef float f32x4 __attribute__((ext_vector_type(4)));
typedef float f32x16 __attribute__((ext_vector_type(16)));

// device-global scratch (outside d_ws; fully rewritten every launch)
__device__ short g_wbuf[18874368];  // bf16 weights, all layers: inproj|outw|ffw1|ffw2
__device__ short g_srcb[1048576];   // src as bf16 (16384 x 64)
__device__ short g_inpwb[32768];    // inp_w as bf16 (512 x 64)
__device__ float g_pe[262144];      // positional encoding (512 x 512)
__device__ float g_hpart[256];      // head partials

__device__ inline float b2f(short s) {
  union { unsigned int u; float f; } v;
  v.u = ((unsigned int)(unsigned short)s) << 16;
  return v.f;
}
__device__ inline short f2b(float f) {
  union { float f; unsigned int u; } v; v.f = f;
  unsigned int r = (v.u + 0x7fffu + ((v.u >> 16) & 1u)) >> 16;
  return (short)r;
}
__device__ inline s16x8 pack8(float4 a, float4 b) {
  s16x8 r;
  r[0] = f2b(a.x); r[1] = f2b(a.y); r[2] = f2b(a.z); r[3] = f2b(a.w);
  r[4] = f2b(b.x); r[5] = f2b(b.y); r[6] = f2b(b.z); r[7] = f2b(b.w);
  return r;
}

__device__ inline f32x4 mfma16(s16x8 a, s16x8 b, f32x4 c) {
  return __builtin_amdgcn_mfma_f32_16x16x32_bf16(a, b, c, 0, 0, 0);
}
__device__ inline f32x16 mfma32(s16x8 a, s16x8 b, f32x16 c) {
  return __builtin_amdgcn_mfma_f32_32x32x16_bf16(a, b, c, 0, 0, 0);
}

typedef const __attribute__((address_space(1))) void* as1cptr;
typedef __attribute__((address_space(3))) void* as3ptr;
__device__ inline void gl2lds16(const short* g, short* l) {
  __builtin_amdgcn_global_load_lds((as1cptr)g, (as3ptr)l, 16, 0, 0);
}

// ---------------- fp32 -> bf16 conversion kernels --------------------------
__global__ void __launch_bounds__(256)
cvt2_kernel(const float* __restrict__ i0, const float* __restrict__ i1) {
  const int b = blockIdx.x;
  const float* src; short* dst; int base;
  if (b < 512) { src = i0; dst = g_srcb; base = b; }
  else         { src = i1; dst = g_inpwb; base = b - 512; }
  const int idx = (base * 256 + threadIdx.x) * 8;
  float4 a = *(const float4*)(src + idx);
  float4 c = *(const float4*)(src + idx + 4);
  *(s16x8*)(dst + idx) = pack8(a, c);
}

// all 6 layers' weights: inproj(2304) | outw(768) | ffw1(3072) | ffw2(3072)
__global__ void __launch_bounds__(256)
cvt6_kernel(const float* __restrict__ i0, const float* __restrict__ i1,
            const float* __restrict__ i2, const float* __restrict__ i3) {
  const int b = blockIdx.x;
  const float* src; short* dst; int base;
  if (b < 2304)      { src = i0; dst = g_wbuf;            base = b; }
  else if (b < 3072) { src = i1; dst = g_wbuf +  4718592; base = b - 2304; }
  else if (b < 6144) { src = i2; dst = g_wbuf +  6291456; base = b - 3072; }
  else               { src = i3; dst = g_wbuf + 12582912; base = b - 6144; }
  const int idx = (base * 256 + threadIdx.x) * 8;
  float4 a = *(const float4*)(src + idx);
  float4 c = *(const float4*)(src + idx + 4);
  *(s16x8*)(dst + idx) = pack8(a, c);
}

// ---------------- PE table: g_pe[s][n] ------------------------------------
__global__ void __launch_bounds__(256)
pe_kernel() {
  const int s = blockIdx.x;
  const int n0 = threadIdx.x * 2;
  const float ang = (float)s * expf((float)n0 * -0.0179889460390160f);
  g_pe[s * 512 + n0]     = sinf(ang);
  g_pe[s * 512 + n0 + 1] = cosf(ang);
}

// ---------------- GEMM: C[M,N] = A[M,K] @ W[N,K]^T + epilogue -------------
// BK=64, XOR-swizzled gl2lds staging. Grid remap (R6, confirmed ~-100us):
// supertiles of 32 bm-panels x all bn keep the in-flight working set at
// ~4MB A slice + <=2MB weights (L2/L3-hot). EPI: 0=+bias; 1=relu; 2=embed.
template <int EPI>
__global__ void __launch_bounds__(256, 3)
gemm_bt(const short* __restrict__ Ain, int woff, const float* __restrict__ bias,
        short* __restrict__ C, int M, int N, int K) {
  __shared__ short As[128 * 64];   // 16 KB
  __shared__ short Bs[128 * 64];   // 16 KB
  const int tid  = threadIdx.x;
  const int lane = tid & 63;
  const int wave = tid >> 6;
  const int wr = (wave >> 1) << 6;
  const int wc = (wave & 1) << 6;
  const int l31 = lane & 31;
  const int half = lane >> 5;          // 0/1: k-half within K=16 step
  const int bnc = N >> 7;              // bn panel count
  const int per = bnc << 5;            // 32 * bnc blocks per supertile
  const int g   = blockIdx.x / per;    // supertile 0..3
  const int rix = blockIdx.x - g * per;
  const int bm  = (g << 5) + (rix & 31);
  const int bn  = rix >> 5;

  const short* A = (EPI == 2) ? (const short*)g_srcb : Ain;
  const short* W = (EPI == 2) ? (const short*)g_inpwb : (const short*)(g_wbuf + woff);

  int srow[4], soff[4];
#pragma unroll
  for (int i = 0; i < 4; ++i) {
    const int u = i * 256 + tid;
    srow[i] = u >> 3;
    soff[i] = ((u & 7) ^ ((u >> 3) & 7)) << 3;
  }
  const int rsw = lane & 7;            // read-side swizzle key (row&7)
  f32x16 acc[2][2] = {};

  for (int k0 = 0; k0 < K; k0 += 64) {
#pragma unroll
    for (int i = 0; i < 4; ++i) {
      gl2lds16(A + (size_t)(bm * 128 + srow[i]) * K + k0 + soff[i],
               As + (i * 256 + tid) * 8);
      gl2lds16(W + (size_t)(bn * 128 + srow[i]) * K + k0 + soff[i],
               Bs + (i * 256 + tid) * 8);
    }
    __syncthreads();
#pragma unroll
    for (int ks = 0; ks < 4; ++ks) {
      const int rchunk = ((ks * 2 + half) ^ rsw) * 8;
      s16x8 af[2], bfr[2];
#pragma unroll
      for (int i = 0; i < 2; ++i)
        af[i] = *(const s16x8*)(As + (wr + i * 32 + l31) * 64 + rchunk);
#pragma unroll
      for (int j = 0; j < 2; ++j)
        bfr[j] = *(const s16x8*)(Bs + (wc + j * 32 + l31) * 64 + rchunk);
#pragma unroll
      for (int i = 0; i < 2; ++i)
#pragma unroll
        for (int j = 0; j < 2; ++j)
          acc[i][j] = mfma32(af[i], bfr[j], acc[i][j]);
    }
    __syncthreads();
  }

#pragma unroll
  for (int j = 0; j < 2; ++j) {
    const int col = bn * 128 + wc + j * 32 + l31;
    const float bv = bias[col];
#pragma unroll
    for (int i = 0; i < 2; ++i) {
      const int rbase = bm * 128 + wr + i * 32 + half * 4;
#pragma unroll
      for (int r = 0; r < 16; ++r) {
        const int row = rbase + (r & 3) + 8 * (r >> 2);
        float v = acc[i][j][r] + bv;
        if (EPI == 1) v = fmaxf(v, 0.0f);
        if (EPI == 2) {
          const int s = row & 511;
          v = (acc[i][j][r] + bv) * 22.62741699796952f + g_pe[s * 512 + col];
        }
        C[(size_t)row * N + col] = f2b(v);
      }
    }
  }
}

// ---------------- attention: v14 = v12 (fixed-max v13 REFUTED) ------------
// v13 post-mortem: layer-0 attention reads x BEFORE any LN; x carries the
// sqrt(D)=22.6 embedding scale, so scores are O(+-100), not O(+-1) — the
// row-max machinery is structurally necessary. Reverted to the verified
// v12: v7 schedule (3 barriers/round, online softmax, single-Kb staging
// after B1) + arithmetic trims (Q pre-scaled by 0.125 exactly; denominator
// via ones-column MFMA summing the same truncated Pt that PV consumes).
// Measured R10: attn 61.4us, VALU 46%, Mfma 13.3%, VGPR 56, no spills,
// absmax 0.0078 (passes).
__global__ void __launch_bounds__(512, 4)
attn_kernel(const short* __restrict__ qkv, short* __restrict__ ctx) {
  __shared__ short Kb[8192];         // K [128 key][64 d], chunk-swizzled
  __shared__ short VT[8192];         // V^T [64 d][128 key], swizzled
  __shared__ short Pt[8192];         // P [64 q][128 key], swizzled
  __shared__ float rcomb[2][4][16];  // [nh][mt][row16]: per-round max
  const int tid = threadIdx.x;
  const int lane = tid & 63, wave = tid >> 6;
  const int ml = lane & 15, quad = lane >> 4;
  const int mt = wave >> 1, nh = wave & 1;
  const int qt = (blockIdx.x >> 3) & 7;
  const int bh = (blockIdx.x & 7) | ((blockIdx.x >> 6) << 3);
  const int b = bh >> 3, h = bh & 7;
  const size_t basebs = (size_t)b * 512 * 1536;
  const int hoff = h * 64;

  // Q fragments, pre-scaled by 0.125 (exact: exponent-3; f2b exact here)
  s16x8 qf0, qf1;
  {
    const int qrow = qt * 64 + mt * 16 + ml;
    const short* qp = qkv + basebs + (size_t)qrow * 1536 + hoff;
    qf0 = *(const s16x8*)(qp + quad * 8);
    qf1 = *(const s16x8*)(qp + 32 + quad * 8);
#pragma unroll
    for (int e = 0; e < 8; ++e) {
      qf0[e] = f2b(b2f(qf0[e]) * 0.125f);
      qf1[e] = f2b(b2f(qf1[e]) * 0.125f);
    }
  }

  // ones fragment (bf16 1.0) for the psum MFMA column
  s16x8 onesf;
#pragma unroll
  for (int e = 0; e < 8; ++e) onesf[e] = (short)0x3F80;

  // K staging geometry: tile [128 key][64 d], 2 gl2lds16 per thread.
  // LDS slot u holds global d-chunk (u&7)^(row&7) of key-row u>>3.
  const int srow0 = tid >> 3, srow1 = srow0 + 64;
  const int soff0 = (((tid & 7) ^ (srow0 & 7)) << 3);
  const int soff1 = (((tid & 7) ^ (srow1 & 7)) << 3);
  const short* kbase = qkv + basebs + 512 + hoff;

  // V geometry: thread covers keys {2*vkp, 2*vkp+1} x d [vd8, vd8+8)
  const int vkp = tid & 63, vd8 = (tid >> 6) << 3;
  const short* vbase = qkv + basebs + 1024 + hoff + vd8;

  // prologue: stage K(0)
  gl2lds16(kbase + (size_t)srow0 * 1536 + soff0, &Kb[tid * 8]);
  gl2lds16(kbase + (size_t)srow1 * 1536 + soff1, &Kb[(512 + tid) * 8]);
  __syncthreads();

  f32x4 oacc[2] = {};
  f32x4 psacc = {};                  // softmax denominator via ones-column MFMA
  float mrun[4] = {-1e30f, -1e30f, -1e30f, -1e30f};

#pragma unroll 1
  for (int rr = 0; rr < 4; ++rr) {
    // issue V(rr) loads; QK^T below hides the latency; consumed this round
    const short* vp = vbase + (size_t)(rr * 128 + vkp * 2) * 1536;
    s16x8 va = *(const s16x8*)vp;
    s16x8 vb = *(const s16x8*)(vp + 1536);

    // QK^T (pre-scaled): 4 nt tiles x (2 mfma)
    f32x4 sc[4];
#pragma unroll
    for (int nt = 0; nt < 4; ++nt) {
      const int krow = nh * 64 + nt * 16 + ml;
      const short* kr = Kb + krow * 64;
      s16x8 kf0 = *(const s16x8*)(kr + ((quad ^ (ml & 7)) << 3));
      s16x8 kf1 = *(const s16x8*)(kr + (((quad + 4) ^ (ml & 7)) << 3));
      f32x4 s0 = {};
      s0 = mfma16(qf0, kf0, s0);
      s0 = mfma16(qf1, kf1, s0);
      sc[nt] = s0;
    }

    // build swizzled V^T(rr) in LDS (va/vb consumed here; no barrier crossed)
#pragma unroll
    for (int j = 0; j < 8; ++j) {
      const int d = vd8 + j;
      unsigned int u = (unsigned int)(unsigned short)va[j]
                     | ((unsigned int)(unsigned short)vb[j] << 16);
      *(unsigned int*)(VT + d * 128 + ((((vkp >> 2) ^ (d & 15)) << 3) | ((vkp & 3) << 1))) = u;
    }

    // wave-local tile row max over this round's 64 keys (per nh half)
    f32x4 tmx = sc[0];
#pragma unroll
    for (int nt = 1; nt < 4; ++nt)
#pragma unroll
      for (int r = 0; r < 4; ++r)
        tmx[r] = fmaxf(tmx[r], sc[nt][r]);
#pragma unroll
    for (int off = 1; off <= 8; off <<= 1)
#pragma unroll
      for (int r = 0; r < 4; ++r)
        tmx[r] = fmaxf(tmx[r], __shfl_xor(tmx[r], off));
    if (ml == 0) {
#pragma unroll
      for (int r = 0; r < 4; ++r)
        rcomb[nh][mt][quad * 4 + r] = tmx[r];
    }
    __syncthreads();                 // B1: rcomb + V^T(rr) visible; Kb reads done

    // stage K(rr+1) into the single Kb; lands during exp phase, drained at B2
    if (rr < 3) {
      const short* kb2 = kbase + (size_t)((rr + 1) * 128) * 1536;
      gl2lds16(kb2 + (size_t)srow0 * 1536 + soff0, &Kb[tid * 8]);
      gl2lds16(kb2 + (size_t)srow1 * 1536 + soff1, &Kb[(512 + tid) * 8]);
    }

    // online rescale (scores already scaled; no 0.125 factor)
#pragma unroll
    for (int r = 0; r < 4; ++r) {
      const float tm = fmaxf(rcomb[0][mt][quad * 4 + r],
                             rcomb[1][mt][quad * 4 + r]);
      const float mn = fmaxf(mrun[r], tm);
      const float scl = __expf(mrun[r] - mn);   // <=1; first round: exp(-huge)=0
      mrun[r] = mn;
      psacc[r] *= scl;
      oacc[0][r] *= scl;
      oacc[1][r] *= scl;
    }

    // exp -> swizzled Pt (truncation to bf16; denominator comes from the
    // ones-column MFMA below, summing the SAME truncated values PV uses)
#pragma unroll
    for (int nt = 0; nt < 4; ++nt) {
#pragma unroll
      for (int r = 0; r < 4; ++r) {
        union { float f; unsigned int u; } pu;
        pu.f = __expf(sc[nt][r] - mrun[r]);   // arg <= 0 exactly
        const short pb = (short)(pu.u >> 16);
        const int qrl = mt * 16 + quad * 4 + r;
        const int c = nh * 64 + nt * 16 + ml;
        Pt[qrl * 128 + ((((c >> 3) ^ (qrl & 15)) << 3) | (c & 7))] = pb;
      }
    }
    __syncthreads();                 // B2: Pt visible; K(rr+1) staged

    // PV + denominator: 4 k-chunks x (ones + 2 d-tiles)
    const int prow = mt * 16 + ml;
#pragma unroll
    for (int ks = 0; ks < 4; ++ks) {
      s16x8 pf = *(const s16x8*)(Pt + prow * 128 + ((((ks << 2) | quad) ^ ml) << 3));
      psacc = mfma16(pf, onesf, psacc);   // sum of P over this 32-key chunk
#pragma unroll
      for (int n2 = 0; n2 < 2; ++n2) {
        const int nd = (nh * 2 + n2) * 16 + ml;
        s16x8 vf = *(const s16x8*)(VT + nd * 128 + ((((ks << 2) | quad) ^ ml) << 3));
        oacc[n2] = mfma16(pf, vf, oacc[n2]);
      }
    }
    __syncthreads();                 // B3: PV reads done before next VT/Pt rewrite
  }

  // psacc[r] holds the FULL 512-key denominator for q-row quad*4+r:
  // each PV pass spans all 128 keys (both nh halves) and rounds cover 4x128.
  // Every lane's psacc is valid (all 16 output cols of the ones-MFMA equal).
#pragma unroll
  for (int r = 0; r < 4; ++r) {
    const float rl = 1.0f / psacc[r];
    const int grow = qt * 64 + mt * 16 + quad * 4 + r;
#pragma unroll
    for (int n2 = 0; n2 < 2; ++n2) {
      const int d = (nh * 2 + n2) * 16 + ml;
      ctx[((size_t)b * 512 + grow) * 512 + hoff + d] = f2b(oacc[n2][r] * rl);
    }
  }
}

// ---------------- residual + layernorm (in-place on x, fp32 params) -------
__global__ void __launch_bounds__(256)
ln_kernel(short* __restrict__ x, const short* __restrict__ o,
          const float* __restrict__ g, const float* __restrict__ bta) {
  const int row = blockIdx.x * 4 + (threadIdx.x >> 6);
  const int lane = threadIdx.x & 63;
  short* xp = x + (size_t)row * 512 + lane * 8;
  const short* op = o + (size_t)row * 512 + lane * 8;
  s16x8 xv = *(const s16x8*)xp;
  s16x8 ov = *(const s16x8*)op;
  float v[8]; float s = 0.f, s2 = 0.f;
#pragma unroll
  for (int e = 0; e < 8; ++e) {
    float f = b2f(xv[e]) + b2f(ov[e]);
    v[e] = f; s += f; s2 += f * f;
  }
#pragma unroll
  for (int off = 32; off >= 1; off >>= 1) {
    s += __shfl_xor(s, off);
    s2 += __shfl_xor(s2, off);
  }
  const float mean = s * (1.f / 512.f);
  const float var = s2 * (1.f / 512.f) - mean * mean;
  const float rstd = rsqrtf(var + 1e-5f);
  float4 g0 = *(const float4*)(g + lane * 8);
  float4 g1 = *(const float4*)(g + lane * 8 + 4);
  float4 b0 = *(const float4*)(bta + lane * 8);
  float4 b1 = *(const float4*)(bta + lane * 8 + 4);
  float gv[8] = {g0.x, g0.y, g0.z, g0.w, g1.x, g1.y, g1.z, g1.w};
  float bv[8] = {b0.x, b0.y, b0.z, b0.w, b1.x, b1.y, b1.z, b1.w};
  s16x8 outv;
#pragma unroll
  for (int e = 0; e < 8; ++e)
    outv[e] = f2b((v[e] - mean) * rstd * gv[e] + bv[e]);
  *(s16x8*)xp = outv;
}

// ---------------- head ----------------------------------------------------
__global__ void __launch_bounds__(256)
head1_kernel(const short* __restrict__ x, const float* __restrict__ w1,
             const float* __restrict__ b1, const float* __restrict__ w2) {
  const int bidx = blockIdx.x;
  const int b = bidx >> 3, seg = bidx & 7;
  const int tid = threadIdx.x;
  __shared__ float xl[512];
  __shared__ float red[256];
  for (int n = tid; n < 512; n += 256)
    xl[n] = b2f(x[((size_t)b * 512 + 511) * 512 + n]);
  __syncthreads();
  const int f = seg * 256 + tid;
  const float* wr = w1 + (size_t)f * 512;
  float hv = 0.f;
  for (int k8 = 0; k8 < 64; ++k8) {
    float4 wa = *(const float4*)(wr + k8 * 8);
    float4 wb = *(const float4*)(wr + k8 * 8 + 4);
    hv += xl[k8 * 8 + 0] * wa.x + xl[k8 * 8 + 1] * wa.y +
          xl[k8 * 8 + 2] * wa.z + xl[k8 * 8 + 3] * wa.w +
          xl[k8 * 8 + 4] * wb.x + xl[k8 * 8 + 5] * wb.y +
          xl[k8 * 8 + 6] * wb.z + xl[k8 * 8 + 7] * wb.w;
  }
  hv += b1[f];
  hv = fmaxf(hv, 0.f);
  red[tid] = hv * w2[f];
  __syncthreads();
  for (int stride = 128; stride > 0; stride >>= 1) {
    if (tid < stride) red[tid] += red[tid + stride];
    __syncthreads();
  }
  if (tid == 0) g_hpart[bidx] = red[0];
}

__global__ void __launch_bounds__(64)
head2_kernel(const float* __restrict__ b2, float* __restrict__ out) {
  const int t = threadIdx.x;
  if (t < 32) {
    float s = 0.f;
#pragma unroll
    for (int c = 0; c < 8; ++c) s += g_hpart[t * 8 + c];
    out[t] = s + b2[0];
  }
}

extern "C" void kernel_launch(void* const* d_in, const int* in_sizes, int n_in,
                              void* d_out, int out_size, void* d_ws, size_t ws_size,
                              hipStream_t stream) {
  (void)in_sizes; (void)n_in; (void)out_size; (void)ws_size;
  const float* src       = (const float*)d_in[0];
  const float* inp_w     = (const float*)d_in[1];
  const float* inp_b     = (const float*)d_in[2];
  const float* in_proj_w = (const float*)d_in[3];
  const float* in_proj_b = (const float*)d_in[4];
  const float* out_w     = (const float*)d_in[5];
  const float* out_b     = (const float*)d_in[6];
  const float* ff_w1     = (const float*)d_in[7];
  const float* ff_b1     = (const float*)d_in[8];
  const float* ff_w2     = (const float*)d_in[9];
  const float* ff_b2     = (const float*)d_in[10];
  const float* ln1_g     = (const float*)d_in[11];
  const float* ln1_b     = (const float*)d_in[12];
  const float* ln2_g     = (const float*)d_in[13];
  const float* ln2_b     = (const float*)d_in[14];
  const float* op_w1     = (const float*)d_in[15];
  const float* op_b1     = (const float*)d_in[16];
  const float* op_w2     = (const float*)d_in[17];
  const float* op_b2     = (const float*)d_in[18];

  short* ws   = (short*)d_ws;
  short* x    = ws;                              //  8,388,608
  short* qkv  = ws + 8388608;                    // 25,165,824
  short* ctx  = qkv + 25165824;                  //  8,388,608
  short* obuf = ctx + 8388608;                   //  8,388,608
  short* h    = qkv;                             // ff hidden spans qkv+ctx

  cvt2_kernel<<<528, 256, 0, stream>>>(src, inp_w);
  cvt6_kernel<<<9216, 256, 0, stream>>>(in_proj_w, out_w, ff_w1, ff_w2);
  pe_kernel<<<512, 256, 0, stream>>>();
  gemm_bt<2><<<512, 256, 0, stream>>>(nullptr, 0, inp_b, x, 16384, 512, 64);

  for (int l = 0; l < 6; ++l) {
    const int w_qkv = l * 786432;
    const int w_out = 4718592 + l * 262144;
    const int w_ff1 = 6291456 + l * 1048576;
    const int w_ff2 = 12582912 + l * 1048576;
    gemm_bt<0><<<1536, 256, 0, stream>>>(
        x, w_qkv, in_proj_b + l * 1536, qkv, 16384, 1536, 512);
    attn_kernel<<<2048, 512, 0, stream>>>(qkv, ctx);
    gemm_bt<0><<<512, 256, 0, stream>>>(
        ctx, w_out, out_b + l * 512, obuf, 16384, 512, 512);
    ln_kernel<<<4096, 256, 0, stream>>>(x, obuf, ln1_g + l * 512, ln1_b + l * 512);
    gemm_bt<1><<<2048, 256, 0, stream>>>(
        x, w_ff1, ff_b1 + l * 2048, h, 16384, 2048, 512);
    gemm_bt<0><<<512, 256, 0, stream>>>(
        h, w_ff2, ff_b2 + l * 512, obuf, 16384, 512, 2048);
    ln_kernel<<<4096, 256, 0, stream>>>(x, obuf, ln2_g + l * 512, ln2_b + l * 512);
  }
  head1_kernel<<<256, 256, 0, stream>>>(x, op_w1, op_b1, op_w2);
  head2_kernel<<<1, 64, 0, stream>>>(op_b2, (float*)d_out);
}

// Round 13
// 1426.167 us; speedup vs baseline: 1.0448x; 1.0024x over previous
//
#include <hip/hip_runtime.h>

typedef short s16x8 __attribute__((ext_vector_type(8)));
typedef float f32x4 __attribute__((ext_vector_type(4)));
typedef float f32x16 __attribute__((ext_vector_type(16)));

// device-global scratch (outside d_ws; fully rewritten every launch)
__device__ short g_wbuf[18874368];  // bf16 weights, all layers: inproj|outw|ffw1|ffw2
__device__ short g_srcb[1048576];   // src as bf16 (16384 x 64)
__device__ short g_inpwb[32768];    // inp_w as bf16 (512 x 64)
__device__ float g_pe[262144];      // positional encoding (512 x 512)
__device__ float g_hpart[256];      // head partials

__device__ inline float b2f(short s) {
  union { unsigned int u; float f; } v;
  v.u = ((unsigned int)(unsigned short)s) << 16;
  return v.f;
}
__device__ inline short f2b(float f) {
  union { float f; unsigned int u; } v; v.f = f;
  unsigned int r = (v.u + 0x7fffu + ((v.u >> 16) & 1u)) >> 16;
  return (short)r;
}
__device__ inline s16x8 pack8(float4 a, float4 b) {
  s16x8 r;
  r[0] = f2b(a.x); r[1] = f2b(a.y); r[2] = f2b(a.z); r[3] = f2b(a.w);
  r[4] = f2b(b.x); r[5] = f2b(b.y); r[6] = f2b(b.z); r[7] = f2b(b.w);
  return r;
}

__device__ inline f32x4 mfma16(s16x8 a, s16x8 b, f32x4 c) {
  return __builtin_amdgcn_mfma_f32_16x16x32_bf16(a, b, c, 0, 0, 0);
}
__device__ inline f32x16 mfma32(s16x8 a, s16x8 b, f32x16 c) {
  return __builtin_amdgcn_mfma_f32_32x32x16_bf16(a, b, c, 0, 0, 0);
}

typedef const __attribute__((address_space(1))) void* as1cptr;
typedef __attribute__((address_space(3))) void* as3ptr;
__device__ inline void gl2lds16(const short* g, short* l) {
  __builtin_amdgcn_global_load_lds((as1cptr)g, (as3ptr)l, 16, 0, 0);
}

// ---------------- fp32 -> bf16 conversion kernels --------------------------
__global__ void __launch_bounds__(256)
cvt2_kernel(const float* __restrict__ i0, const float* __restrict__ i1) {
  const int b = blockIdx.x;
  const float* src; short* dst; int base;
  if (b < 512) { src = i0; dst = g_srcb; base = b; }
  else         { src = i1; dst = g_inpwb; base = b - 512; }
  const int idx = (base * 256 + threadIdx.x) * 8;
  float4 a = *(const float4*)(src + idx);
  float4 c = *(const float4*)(src + idx + 4);
  *(s16x8*)(dst + idx) = pack8(a, c);
}

// all 6 layers' weights: inproj(2304) | outw(768) | ffw1(3072) | ffw2(3072)
__global__ void __launch_bounds__(256)
cvt6_kernel(const float* __restrict__ i0, const float* __restrict__ i1,
            const float* __restrict__ i2, const float* __restrict__ i3) {
  const int b = blockIdx.x;
  const float* src; short* dst; int base;
  if (b < 2304)      { src = i0; dst = g_wbuf;            base = b; }
  else if (b < 3072) { src = i1; dst = g_wbuf +  4718592; base = b - 2304; }
  else if (b < 6144) { src = i2; dst = g_wbuf +  6291456; base = b - 3072; }
  else               { src = i3; dst = g_wbuf + 12582912; base = b - 6144; }
  const int idx = (base * 256 + threadIdx.x) * 8;
  float4 a = *(const float4*)(src + idx);
  float4 c = *(const float4*)(src + idx + 4);
  *(s16x8*)(dst + idx) = pack8(a, c);
}

// ---------------- PE table: g_pe[s][n] ------------------------------------
__global__ void __launch_bounds__(256)
pe_kernel() {
  const int s = blockIdx.x;
  const int n0 = threadIdx.x * 2;
  const float ang = (float)s * expf((float)n0 * -0.0179889460390160f);
  g_pe[s * 512 + n0]     = sinf(ang);
  g_pe[s * 512 + n0 + 1] = cosf(ang);
}

// ---------------- GEMM: C[M,N] = A[M,K] @ W[N,K]^T + epilogue -------------
// BK=64, XOR-swizzled gl2lds staging. Grid remap (R6, confirmed ~-100us):
// supertiles of 32 bm-panels x all bn keep the in-flight working set at
// ~4MB A slice + <=2MB weights (L2/L3-hot). EPI: 0=+bias; 1=relu; 2=embed.
template <int EPI>
__global__ void __launch_bounds__(256, 3)
gemm_bt(const short* __restrict__ Ain, int woff, const float* __restrict__ bias,
        short* __restrict__ C, int M, int N, int K) {
  __shared__ short As[128 * 64];   // 16 KB
  __shared__ short Bs[128 * 64];   // 16 KB
  const int tid  = threadIdx.x;
  const int lane = tid & 63;
  const int wave = tid >> 6;
  const int wr = (wave >> 1) << 6;
  const int wc = (wave & 1) << 6;
  const int l31 = lane & 31;
  const int half = lane >> 5;          // 0/1: k-half within K=16 step
  const int bnc = N >> 7;              // bn panel count
  const int per = bnc << 5;            // 32 * bnc blocks per supertile
  const int g   = blockIdx.x / per;    // supertile 0..3
  const int rix = blockIdx.x - g * per;
  const int bm  = (g << 5) + (rix & 31);
  const int bn  = rix >> 5;

  const short* A = (EPI == 2) ? (const short*)g_srcb : Ain;
  const short* W = (EPI == 2) ? (const short*)g_inpwb : (const short*)(g_wbuf + woff);

  int srow[4], soff[4];
#pragma unroll
  for (int i = 0; i < 4; ++i) {
    const int u = i * 256 + tid;
    srow[i] = u >> 3;
    soff[i] = ((u & 7) ^ ((u >> 3) & 7)) << 3;
  }
  const int rsw = lane & 7;            // read-side swizzle key (row&7)
  f32x16 acc[2][2] = {};

  for (int k0 = 0; k0 < K; k0 += 64) {
#pragma unroll
    for (int i = 0; i < 4; ++i) {
      gl2lds16(A + (size_t)(bm * 128 + srow[i]) * K + k0 + soff[i],
               As + (i * 256 + tid) * 8);
      gl2lds16(W + (size_t)(bn * 128 + srow[i]) * K + k0 + soff[i],
               Bs + (i * 256 + tid) * 8);
    }
    __syncthreads();
#pragma unroll
    for (int ks = 0; ks < 4; ++ks) {
      const int rchunk = ((ks * 2 + half) ^ rsw) * 8;
      s16x8 af[2], bfr[2];
#pragma unroll
      for (int i = 0; i < 2; ++i)
        af[i] = *(const s16x8*)(As + (wr + i * 32 + l31) * 64 + rchunk);
#pragma unroll
      for (int j = 0; j < 2; ++j)
        bfr[j] = *(const s16x8*)(Bs + (wc + j * 32 + l31) * 64 + rchunk);
#pragma unroll
      for (int i = 0; i < 2; ++i)
#pragma unroll
        for (int j = 0; j < 2; ++j)
          acc[i][j] = mfma32(af[i], bfr[j], acc[i][j]);
    }
    __syncthreads();
  }

#pragma unroll
  for (int j = 0; j < 2; ++j) {
    const int col = bn * 128 + wc + j * 32 + l31;
    const float bv = bias[col];
#pragma unroll
    for (int i = 0; i < 2; ++i) {
      const int rbase = bm * 128 + wr + i * 32 + half * 4;
#pragma unroll
      for (int r = 0; r < 16; ++r) {
        const int row = rbase + (r & 3) + 8 * (r >> 2);
        float v = acc[i][j][r] + bv;
        if (EPI == 1) v = fmaxf(v, 0.0f);
        if (EPI == 2) {
          const int s = row & 511;
          v = (acc[i][j][r] + bv) * 22.62741699796952f + g_pe[s * 512 + col];
        }
        C[(size_t)row * N + col] = f2b(v);
      }
    }
  }
}

// ---------------- attention: v15 = v12 + T5 setprio on MFMA clusters ------
// v12 (verified R10/R12: attn 61-63us, VGPR 56, no spills) with ONLY
// __builtin_amdgcn_s_setprio(1)/(0) wrapped around the two MFMA clusters.
// Mechanism (T5, structure-conditional): ~1.5-3 blocks/CU co-resident at
// independent phases; priority lets the scheduler favor the block entering
// its MFMA cluster over the other block's load/VALU phase. Guide: +4-7%
// on attn with phase diversity (m191), null on lockstep (m190) — this is
// the discriminating experiment. Zero correctness/liveness risk.
__global__ void __launch_bounds__(512, 4)
attn_kernel(const short* __restrict__ qkv, short* __restrict__ ctx) {
  __shared__ short Kb[8192];         // K [128 key][64 d], chunk-swizzled
  __shared__ short VT[8192];         // V^T [64 d][128 key], swizzled
  __shared__ short Pt[8192];         // P [64 q][128 key], swizzled
  __shared__ float rcomb[2][4][16];  // [nh][mt][row16]: per-round max
  const int tid = threadIdx.x;
  const int lane = tid & 63, wave = tid >> 6;
  const int ml = lane & 15, quad = lane >> 4;
  const int mt = wave >> 1, nh = wave & 1;
  const int qt = (blockIdx.x >> 3) & 7;
  const int bh = (blockIdx.x & 7) | ((blockIdx.x >> 6) << 3);
  const int b = bh >> 3, h = bh & 7;
  const size_t basebs = (size_t)b * 512 * 1536;
  const int hoff = h * 64;

  // Q fragments, pre-scaled by 0.125 (exact: exponent-3; f2b exact here)
  s16x8 qf0, qf1;
  {
    const int qrow = qt * 64 + mt * 16 + ml;
    const short* qp = qkv + basebs + (size_t)qrow * 1536 + hoff;
    qf0 = *(const s16x8*)(qp + quad * 8);
    qf1 = *(const s16x8*)(qp + 32 + quad * 8);
#pragma unroll
    for (int e = 0; e < 8; ++e) {
      qf0[e] = f2b(b2f(qf0[e]) * 0.125f);
      qf1[e] = f2b(b2f(qf1[e]) * 0.125f);
    }
  }

  // ones fragment (bf16 1.0) for the psum MFMA column
  s16x8 onesf;
#pragma unroll
  for (int e = 0; e < 8; ++e) onesf[e] = (short)0x3F80;

  // K staging geometry: tile [128 key][64 d], 2 gl2lds16 per thread.
  // LDS slot u holds global d-chunk (u&7)^(row&7) of key-row u>>3.
  const int srow0 = tid >> 3, srow1 = srow0 + 64;
  const int soff0 = (((tid & 7) ^ (srow0 & 7)) << 3);
  const int soff1 = (((tid & 7) ^ (srow1 & 7)) << 3);
  const short* kbase = qkv + basebs + 512 + hoff;

  // V geometry: thread covers keys {2*vkp, 2*vkp+1} x d [vd8, vd8+8)
  const int vkp = tid & 63, vd8 = (tid >> 6) << 3;
  const short* vbase = qkv + basebs + 1024 + hoff + vd8;

  // prologue: stage K(0)
  gl2lds16(kbase + (size_t)srow0 * 1536 + soff0, &Kb[tid * 8]);
  gl2lds16(kbase + (size_t)srow1 * 1536 + soff1, &Kb[(512 + tid) * 8]);
  __syncthreads();

  f32x4 oacc[2] = {};
  f32x4 psacc = {};                  // softmax denominator via ones-column MFMA
  float mrun[4] = {-1e30f, -1e30f, -1e30f, -1e30f};

#pragma unroll 1
  for (int rr = 0; rr < 4; ++rr) {
    // issue V(rr) loads; QK^T below hides the latency; consumed this round
    const short* vp = vbase + (size_t)(rr * 128 + vkp * 2) * 1536;
    s16x8 va = *(const s16x8*)vp;
    s16x8 vb = *(const s16x8*)(vp + 1536);

    // QK^T (pre-scaled): 4 nt tiles x (2 mfma), priority-boosted
    f32x4 sc[4];
    __builtin_amdgcn_s_setprio(1);
#pragma unroll
    for (int nt = 0; nt < 4; ++nt) {
      const int krow = nh * 64 + nt * 16 + ml;
      const short* kr = Kb + krow * 64;
      s16x8 kf0 = *(const s16x8*)(kr + ((quad ^ (ml & 7)) << 3));
      s16x8 kf1 = *(const s16x8*)(kr + (((quad + 4) ^ (ml & 7)) << 3));
      f32x4 s0 = {};
      s0 = mfma16(qf0, kf0, s0);
      s0 = mfma16(qf1, kf1, s0);
      sc[nt] = s0;
    }
    __builtin_amdgcn_s_setprio(0);

    // build swizzled V^T(rr) in LDS (va/vb consumed here; no barrier crossed)
#pragma unroll
    for (int j = 0; j < 8; ++j) {
      const int d = vd8 + j;
      unsigned int u = (unsigned int)(unsigned short)va[j]
                     | ((unsigned int)(unsigned short)vb[j] << 16);
      *(unsigned int*)(VT + d * 128 + ((((vkp >> 2) ^ (d & 15)) << 3) | ((vkp & 3) << 1))) = u;
    }

    // wave-local tile row max over this round's 64 keys (per nh half)
    f32x4 tmx = sc[0];
#pragma unroll
    for (int nt = 1; nt < 4; ++nt)
#pragma unroll
      for (int r = 0; r < 4; ++r)
        tmx[r] = fmaxf(tmx[r], sc[nt][r]);
#pragma unroll
    for (int off = 1; off <= 8; off <<= 1)
#pragma unroll
      for (int r = 0; r < 4; ++r)
        tmx[r] = fmaxf(tmx[r], __shfl_xor(tmx[r], off));
    if (ml == 0) {
#pragma unroll
      for (int r = 0; r < 4; ++r)
        rcomb[nh][mt][quad * 4 + r] = tmx[r];
    }
    __syncthreads();                 // B1: rcomb + V^T(rr) visible; Kb reads done

    // stage K(rr+1) into the single Kb; lands during exp phase, drained at B2
    if (rr < 3) {
      const short* kb2 = kbase + (size_t)((rr + 1) * 128) * 1536;
      gl2lds16(kb2 + (size_t)srow0 * 1536 + soff0, &Kb[tid * 8]);
      gl2lds16(kb2 + (size_t)srow1 * 1536 + soff1, &Kb[(512 + tid) * 8]);
    }

    // online rescale (scores already scaled; no 0.125 factor)
#pragma unroll
    for (int r = 0; r < 4; ++r) {
      const float tm = fmaxf(rcomb[0][mt][quad * 4 + r],
                             rcomb[1][mt][quad * 4 + r]);
      const float mn = fmaxf(mrun[r], tm);
      const float scl = __expf(mrun[r] - mn);   // <=1; first round: exp(-huge)=0
      mrun[r] = mn;
      psacc[r] *= scl;
      oacc[0][r] *= scl;
      oacc[1][r] *= scl;
    }

    // exp -> swizzled Pt (truncation to bf16; denominator comes from the
    // ones-column MFMA below, summing the SAME truncated values PV uses)
#pragma unroll
    for (int nt = 0; nt < 4; ++nt) {
#pragma unroll
      for (int r = 0; r < 4; ++r) {
        union { float f; unsigned int u; } pu;
        pu.f = __expf(sc[nt][r] - mrun[r]);   // arg <= 0 exactly
        const short pb = (short)(pu.u >> 16);
        const int qrl = mt * 16 + quad * 4 + r;
        const int c = nh * 64 + nt * 16 + ml;
        Pt[qrl * 128 + ((((c >> 3) ^ (qrl & 15)) << 3) | (c & 7))] = pb;
      }
    }
    __syncthreads();                 // B2: Pt visible; K(rr+1) staged

    // PV + denominator: 4 k-chunks x (ones + 2 d-tiles), priority-boosted
    const int prow = mt * 16 + ml;
    __builtin_amdgcn_s_setprio(1);
#pragma unroll
    for (int ks = 0; ks < 4; ++ks) {
      s16x8 pf = *(const s16x8*)(Pt + prow * 128 + ((((ks << 2) | quad) ^ ml) << 3));
      psacc = mfma16(pf, onesf, psacc);   // sum of P over this 32-key chunk
#pragma unroll
      for (int n2 = 0; n2 < 2; ++n2) {
        const int nd = (nh * 2 + n2) * 16 + ml;
        s16x8 vf = *(const s16x8*)(VT + nd * 128 + ((((ks << 2) | quad) ^ ml) << 3));
        oacc[n2] = mfma16(pf, vf, oacc[n2]);
      }
    }
    __builtin_amdgcn_s_setprio(0);
    __syncthreads();                 // B3: PV reads done before next VT/Pt rewrite
  }

  // psacc[r] holds the FULL 512-key denominator for q-row quad*4+r:
  // each PV pass spans all 128 keys (both nh halves) and rounds cover 4x128.
  // Every lane's psacc is valid (all 16 output cols of the ones-MFMA equal).
#pragma unroll
  for (int r = 0; r < 4; ++r) {
    const float rl = 1.0f / psacc[r];
    const int grow = qt * 64 + mt * 16 + quad * 4 + r;
#pragma unroll
    for (int n2 = 0; n2 < 2; ++n2) {
      const int d = (nh * 2 + n2) * 16 + ml;
      ctx[((size_t)b * 512 + grow) * 512 + hoff + d] = f2b(oacc[n2][r] * rl);
    }
  }
}

// ---------------- residual + layernorm (in-place on x, fp32 params) -------
__global__ void __launch_bounds__(256)
ln_kernel(short* __restrict__ x, const short* __restrict__ o,
          const float* __restrict__ g, const float* __restrict__ bta) {
  const int row = blockIdx.x * 4 + (threadIdx.x >> 6);
  const int lane = threadIdx.x & 63;
  short* xp = x + (size_t)row * 512 + lane * 8;
  const short* op = o + (size_t)row * 512 + lane * 8;
  s16x8 xv = *(const s16x8*)xp;
  s16x8 ov = *(const s16x8*)op;
  float v[8]; float s = 0.f, s2 = 0.f;
#pragma unroll
  for (int e = 0; e < 8; ++e) {
    float f = b2f(xv[e]) + b2f(ov[e]);
    v[e] = f; s += f; s2 += f * f;
  }
#pragma unroll
  for (int off = 32; off >= 1; off >>= 1) {
    s += __shfl_xor(s, off);
    s2 += __shfl_xor(s2, off);
  }
  const float mean = s * (1.f / 512.f);
  const float var = s2 * (1.f / 512.f) - mean * mean;
  const float rstd = rsqrtf(var + 1e-5f);
  float4 g0 = *(const float4*)(g + lane * 8);
  float4 g1 = *(const float4*)(g + lane * 8 + 4);
  float4 b0 = *(const float4*)(bta + lane * 8);
  float4 b1 = *(const float4*)(bta + lane * 8 + 4);
  float gv[8] = {g0.x, g0.y, g0.z, g0.w, g1.x, g1.y, g1.z, g1.w};
  float bv[8] = {b0.x, b0.y, b0.z, b0.w, b1.x, b1.y, b1.z, b1.w};
  s16x8 outv;
#pragma unroll
  for (int e = 0; e < 8; ++e)
    outv[e] = f2b((v[e] - mean) * rstd * gv[e] + bv[e]);
  *(s16x8*)xp = outv;
}

// ---------------- head ----------------------------------------------------
__global__ void __launch_bounds__(256)
head1_kernel(const short* __restrict__ x, const float* __restrict__ w1,
             const float* __restrict__ b1, const float* __restrict__ w2) {
  const int bidx = blockIdx.x;
  const int b = bidx >> 3, seg = bidx & 7;
  const int tid = threadIdx.x;
  __shared__ float xl[512];
  __shared__ float red[256];
  for (int n = tid; n < 512; n += 256)
    xl[n] = b2f(x[((size_t)b * 512 + 511) * 512 + n]);
  __syncthreads();
  const int f = seg * 256 + tid;
  const float* wr = w1 + (size_t)f * 512;
  float hv = 0.f;
  for (int k8 = 0; k8 < 64; ++k8) {
    float4 wa = *(const float4*)(wr + k8 * 8);
    float4 wb = *(const float4*)(wr + k8 * 8 + 4);
    hv += xl[k8 * 8 + 0] * wa.x + xl[k8 * 8 + 1] * wa.y +
          xl[k8 * 8 + 2] * wa.z + xl[k8 * 8 + 3] * wa.w +
          xl[k8 * 8 + 4] * wb.x + xl[k8 * 8 + 5] * wb.y +
          xl[k8 * 8 + 6] * wb.z + xl[k8 * 8 + 7] * wb.w;
  }
  hv += b1[f];
  hv = fmaxf(hv, 0.f);
  red[tid] = hv * w2[f];
  __syncthreads();
  for (int stride = 128; stride > 0; stride >>= 1) {
    if (tid < stride) red[tid] += red[tid + stride];
    __syncthreads();
  }
  if (tid == 0) g_hpart[bidx] = red[0];
}

__global__ void __launch_bounds__(64)
head2_kernel(const float* __restrict__ b2, float* __restrict__ out) {
  const int t = threadIdx.x;
  if (t < 32) {
    float s = 0.f;
#pragma unroll
    for (int c = 0; c < 8; ++c) s += g_hpart[t * 8 + c];
    out[t] = s + b2[0];
  }
}

extern "C" void kernel_launch(void* const* d_in, const int* in_sizes, int n_in,
                              void* d_out, int out_size, void* d_ws, size_t ws_size,
                              hipStream_t stream) {
  (void)in_sizes; (void)n_in; (void)out_size; (void)ws_size;
  const float* src       = (const float*)d_in[0];
  const float* inp_w     = (const float*)d_in[1];
  const float* inp_b     = (const float*)d_in[2];
  const float* in_proj_w = (const float*)d_in[3];
  const float* in_proj_b = (const float*)d_in[4];
  const float* out_w     = (const float*)d_in[5];
  const float* out_b     = (const float*)d_in[6];
  const float* ff_w1     = (const float*)d_in[7];
  const float* ff_b1     = (const float*)d_in[8];
  const float* ff_w2     = (const float*)d_in[9];
  const float* ff_b2     = (const float*)d_in[10];
  const float* ln1_g     = (const float*)d_in[11];
  const float* ln1_b     = (const float*)d_in[12];
  const float* ln2_g     = (const float*)d_in[13];
  const float* ln2_b     = (const float*)d_in[14];
  const float* op_w1     = (const float*)d_in[15];
  const float* op_b1     = (const float*)d_in[16];
  const float* op_w2     = (const float*)d_in[17];
  const float* op_b2     = (const float*)d_in[18];

  short* ws   = (short*)d_ws;
  short* x    = ws;                              //  8,388,608
  short* qkv  = ws + 8388608;                    // 25,165,824
  short* ctx  = qkv + 25165824;                  //  8,388,608
  short* obuf = ctx + 8388608;                   //  8,388,608
  short* h    = qkv;                             // ff hidden spans qkv+ctx

  cvt2_kernel<<<528, 256, 0, stream>>>(src, inp_w);
  cvt6_kernel<<<9216, 256, 0, stream>>>(in_proj_w, out_w, ff_w1, ff_w2);
  pe_kernel<<<512, 256, 0, stream>>>();
  gemm_bt<2><<<512, 256, 0, stream>>>(nullptr, 0, inp_b, x, 16384, 512, 64);

  for (int l = 0; l < 6; ++l) {
    const int w_qkv = l * 786432;
    const int w_out = 4718592 + l * 262144;
    const int w_ff1 = 6291456 + l * 1048576;
    const int w_ff2 = 12582912 + l * 1048576;
    gemm_bt<0><<<1536, 256, 0, stream>>>(
        x, w_qkv, in_proj_b + l * 1536, qkv, 16384, 1536, 512);
    attn_kernel<<<2048, 512, 0, stream>>>(qkv, ctx);
    gemm_bt<0><<<512, 256, 0, stream>>>(
        ctx, w_out, out_b + l * 512, obuf, 16384, 512, 512);
    ln_kernel<<<4096, 256, 0, stream>>>(x, obuf, ln1_g + l * 512, ln1_b + l * 512);
    gemm_bt<1><<<2048, 256, 0, stream>>>(
        x, w_ff1, ff_b1 + l * 2048, h, 16384, 2048, 512);
    gemm_bt<0><<<512, 256, 0, stream>>>(
        h, w_ff2, ff_b2 + l * 512, obuf, 16384, 512, 2048);
    ln_kernel<<<4096, 256, 0, stream>>>(x, obuf, ln2_g + l * 512, ln2_b + l * 512);
  }
  head1_kernel<<<256, 256, 0, stream>>>(x, op_w1, op_b1, op_w2);
  head2_kernel<<<1, 64, 0, stream>>>(op_b2, (float*)d_out);
}